// Round 15
// baseline (224.265 us; speedup 1.0000x reference)
//
#include <hip/hip_runtime.h>
#include <hip/hip_fp16.h>

#define NB 64
#define NS 512
#define NH 1024
#define NITERS 10

// -log(512)
#define LOG_INV_NS (-6.238324625039508f)

using half8 = _Float16 __attribute__((ext_vector_type(8)));
using f32x4 = float __attribute__((ext_vector_type(4)));

// ---------------------------------------------------------------------------
// Fused GEMM: batched cosine scores, f16 out.
// R15: 256x128 tile, 512 thr / 8 waves (4Mx2N, wave = 64x64 -> acc[4][4] =
// 64 AGPR), __launch_bounds__(512,4) caps VGPR at 128 -> 2 BLOCKS/CU.
// Two independent barrier groups per CU: one block's compute fills the
// other's vmcnt/barrier drains (m97-style implicit overlap).
// BK=32 LDS double-buffer, raw s_barrier (R13 discipline), in-kernel norms,
// epilogue normalization, XCD-pinned decode (blk%8 == b%8).
__global__ __launch_bounds__(512, 4) void gemm_fused(
    const float* __restrict__ x, const float* __restrict__ y,
    _Float16* __restrict__ Sh) {
  __shared__ _Float16 As[2][256][40];   // 40960 B
  __shared__ _Float16 Bs[2][128][40];   // 20480 B
  __shared__ float invA[256], invB[128];

  int blk = blockIdx.x;
  int b = blk & 63;                  // batch; blk%8 = b%8 -> XCD pinned
  int tile = blk >> 6;               // 0..7 = 2M x 4N
  int tm = (tile >> 2) * 256, tn = (tile & 3) * 128;
  int tid = threadIdx.x;
  int wid = tid >> 6, lane = tid & 63;
  int wr = (wid >> 1) * 64;          // {0,64,128,192}
  int wc = (wid & 1) * 64;           // {0,64}
  int fr = lane & 15, fq = lane >> 4;

  // A staging: row tid>>1 (0..255), k-half (tid&1)*16 (4 float4 loads)
  int srA = tid >> 1, skA = (tid & 1) * 16;
  // B staging: row tid>>2 (0..127), k-quarter (tid&3)*8 (2 float4 loads)
  int srB = tid >> 2, skB = (tid & 3) * 8;
  const float* xb = x + ((size_t)b * NS + tm + srA) * NH + skA;
  const float* yb = y + ((size_t)b * NS + tn + srB) * NH + skB;

  f32x4 acc[4][4] = {};
  float4 rx[4], ry[2];
  float sqx = 0.f, sqy = 0.f;

#define GLOAD(K0)                                                     \
  do {                                                                \
    const float4* px = (const float4*)(xb + (K0));                    \
    const float4* py = (const float4*)(yb + (K0));                    \
    rx[0] = px[0]; rx[1] = px[1]; rx[2] = px[2]; rx[3] = px[3];       \
    ry[0] = py[0]; ry[1] = py[1];                                     \
  } while (0)

#define CAST_WRITE(BUF)                                               \
  do {                                                                \
    alignas(16) _Float16 ta[16];                                      \
    alignas(16) _Float16 tb[8];                                       \
    _Pragma("unroll") for (int j = 0; j < 4; ++j) {                   \
      float4 v = rx[j];                                               \
      ta[4 * j + 0] = (_Float16)v.x; ta[4 * j + 1] = (_Float16)v.y;   \
      ta[4 * j + 2] = (_Float16)v.z; ta[4 * j + 3] = (_Float16)v.w;   \
      sqx += v.x * v.x + v.y * v.y + v.z * v.z + v.w * v.w;           \
    }                                                                 \
    _Pragma("unroll") for (int j = 0; j < 2; ++j) {                   \
      float4 v = ry[j];                                               \
      tb[4 * j + 0] = (_Float16)v.x; tb[4 * j + 1] = (_Float16)v.y;   \
      tb[4 * j + 2] = (_Float16)v.z; tb[4 * j + 3] = (_Float16)v.w;   \
      sqy += v.x * v.x + v.y * v.y + v.z * v.z + v.w * v.w;           \
    }                                                                 \
    *(half8*)&As[BUF][srA][skA + 0] = *(half8*)&ta[0];                \
    *(half8*)&As[BUF][srA][skA + 8] = *(half8*)&ta[8];                \
    *(half8*)&Bs[BUF][srB][skB] = *(half8*)&tb[0];                    \
  } while (0)

  // prologue: stage chunk 0 into buf 0, issue chunk 1 loads
  GLOAD(0);
  CAST_WRITE(0);
  GLOAD(32);
  asm volatile("s_waitcnt lgkmcnt(0)" ::: "memory");
  __builtin_amdgcn_sched_barrier(0);
  __builtin_amdgcn_s_barrier();
  __builtin_amdgcn_sched_barrier(0);

  for (int s = 0; s < 32; ++s) {
    int cur = s & 1;
    // ---- MFMA phase on buf[cur] (chunk s+1 loads still in flight) ----
    half8 bf[4], af[4];
#pragma unroll
    for (int j = 0; j < 4; ++j)
      bf[j] = *(const half8*)&Bs[cur][wc + 16 * j + fr][8 * fq];
#pragma unroll
    for (int i = 0; i < 4; ++i)
      af[i] = *(const half8*)&As[cur][wr + 16 * i + fr][8 * fq];
#pragma unroll
    for (int i = 0; i < 4; ++i)
#pragma unroll
      for (int j = 0; j < 4; ++j)
        acc[i][j] = __builtin_amdgcn_mfma_f32_16x16x32_f16(af[i], bf[j], acc[i][j], 0, 0, 0);
    // ---- stage chunk s+1 into buf[cur^1]; issue loads for chunk s+2 ----
    if (s < 31) {
      CAST_WRITE(cur ^ 1);             // vmcnt wait lands here (after MFMA)
      if (s < 30) GLOAD((s + 2) * 32);
    }
    asm volatile("s_waitcnt lgkmcnt(0)" ::: "memory");
    __builtin_amdgcn_sched_barrier(0);
    __builtin_amdgcn_s_barrier();
    __builtin_amdgcn_sched_barrier(0);
  }
#undef GLOAD
#undef CAST_WRITE

  // finalize row norms.
  // A: 2 partials per row in lanes (tid, tid^1)
  sqx += __shfl_xor(sqx, 1, 64);
  if ((tid & 1) == 0) invA[srA] = 1.0f / fmaxf(sqrtf(sqx), 1e-12f);
  // B: 4 partials per row in lanes (tid & ~3)+0..3
  sqy += __shfl_xor(sqy, 1, 64);
  sqy += __shfl_xor(sqy, 2, 64);
  if ((tid & 3) == 0) invB[srB] = 1.0f / fmaxf(sqrtf(sqy), 1e-12f);
  __syncthreads();

  // Epilogue: S = acc * invA[m] * invB[n], direct f16 stores.
  // C/D layout: col = lane&15 (n), row = (lane>>4)*4 + reg (m).
  _Float16* Sb = Sh + (size_t)b * NS * NS;
#pragma unroll
  for (int i = 0; i < 4; ++i)
#pragma unroll
    for (int j = 0; j < 4; ++j) {
      int rr = wr + 16 * i + 4 * fq;
      int cc = wc + 16 * j + fr;
      float ib = invB[cc];
#pragma unroll
      for (int p = 0; p < 4; ++p)
        Sb[(size_t)(tm + rr + p) * NS + tn + cc] =
            (_Float16)(acc[i][j][p] * invA[rr + p] * ib);
    }
}

// ---------------------------------------------------------------------------
// Kernel 4 (u/row step): 2048 blocks. first=1 -> W uniformly log(1/NS).
__global__ __launch_bounds__(256) void u_kernel(
    const _Float16* __restrict__ Sh, const float* __restrict__ W,
    float* __restrict__ U, float f, int first) {
  __shared__ float Wt[8][65];
  int blk = blockIdx.x;
  int bs = blk & 7, rest = blk >> 3;
  int rowgrp = rest & 31, bq = rest >> 5;
  int b = bq * 8 + bs;
  int t = threadIdx.x;
  if (!first) {
#pragma unroll
    for (int i = 0; i < 2; ++i) {
      int idx = t + 256 * i;
      Wt[idx & 7][idx >> 3] = W[b * NS + idx];
    }
    __syncthreads();
  }
  int w = t >> 6, l = t & 63;
  float wn[8];
#pragma unroll
  for (int e = 0; e < 8; ++e) wn[e] = first ? LOG_INV_NS : Wt[e][l];
  int m0 = rowgrp * 16 + w * 4;
  const _Float16* Sb = Sh + ((size_t)b * NS + m0) * NS + 8 * l;
  float sum[4] = {0.f, 0.f, 0.f, 0.f};
#pragma unroll
  for (int k = 0; k < 4; ++k) {
    half8 hv = *(const half8*)(Sb + (size_t)k * NS);
#pragma unroll
    for (int e = 0; e < 8; ++e) sum[k] += __expf(fmaf(f, (float)hv[e], wn[e]));
  }
#pragma unroll
  for (int o = 32; o; o >>= 1) {
#pragma unroll
    for (int k = 0; k < 4; ++k) sum[k] += __shfl_xor(sum[k], o, 64);
  }
  if (l == 0) {
#pragma unroll
    for (int k = 0; k < 4; ++k)
      U[b * NS + m0 + k] = LOG_INV_NS - __logf(sum[k]);
  }
}

// ---------------------------------------------------------------------------
// Kernel 5 (v/col step): 1024 blocks, high occupancy. first=1 -> vold = 0.
__global__ __launch_bounds__(256) void v_kernel(
    const _Float16* __restrict__ Sh, const float* __restrict__ U,
    float* __restrict__ V, float* __restrict__ W,
    float f, int first, int last, float* __restrict__ outPart) {
  __shared__ float Ul[NS];
  __shared__ float partC[64][33];
  __shared__ float partD[64][33];
  __shared__ float redC[4][33];
  __shared__ float redD[4][33];
  int blk = blockIdx.x;
  int b = blk & 63;
  int ng = blk >> 6;                // 0..15, 32 cols each
  int t = threadIdx.x;
  Ul[t] = U[b * NS + t];
  Ul[t + 256] = U[b * NS + t + 256];
  __syncthreads();

  int oct = t & 3;
  int mc = t >> 2;                  // m-chunk (8 rows), 0..63
  const _Float16* Sb = Sh + (size_t)b * NS * NS + (size_t)(mc * 8) * NS + ng * 32 + oct * 8;
  float c[8] = {}, d[8] = {};
#pragma unroll
  for (int i = 0; i < 8; ++i) {
    half8 hv = *(const half8*)(Sb + (size_t)i * NS);
    float um = Ul[mc * 8 + i];
#pragma unroll
    for (int e = 0; e < 8; ++e) {
      float sv = (float)hv[e];
      float ev = __expf(fmaf(f, sv, um));
      c[e] += ev;
      d[e] = fmaf(sv, ev, d[e]);
    }
  }
#pragma unroll
  for (int e = 0; e < 8; ++e) {
    partC[mc][oct * 8 + e] = c[e];
    partD[mc][oct * 8 + e] = d[e];
  }
  __syncthreads();
  {
    int ci = t & 31, seg = t >> 5;
    float cc = 0.f, dd = 0.f;
#pragma unroll
    for (int k = 0; k < 8; ++k) {
      cc += partC[seg * 8 + k][ci];
      dd += partD[seg * 8 + k][ci];
    }
    cc += __shfl_xor(cc, 32, 64);
    dd += __shfl_xor(dd, 32, 64);
    int w = t >> 6, l = t & 63;
    if (l < 32) { redC[w][l] = cc; redD[w][l] = dd; }
  }
  __syncthreads();
  if (t < 32) {
    float cc = redC[0][t] + redC[1][t] + redC[2][t] + redC[3][t];
    float vnew = LOG_INV_NS - __logf(cc);
    int n = b * NS + ng * 32 + t;
    float vold = first ? 0.f : V[n];
    V[n] = vnew;
    W[n] = 2.f * vnew - vold;
    if (last) {
      float dd = redD[0][t] + redD[1][t] + redD[2][t] + redD[3][t];
      float r = dd / cc;
      r += __shfl_xor(r, 16, 64);
      r += __shfl_xor(r, 8, 64);
      r += __shfl_xor(r, 4, 64);
      r += __shfl_xor(r, 2, 64);
      r += __shfl_xor(r, 1, 64);
      if (t == 0) outPart[b * 16 + ng] = r * (1.0f / (float)NS);
    }
  }
}

// ---------------------------------------------------------------------------
// Kernel 6: combine 16 partials per batch (deterministic)
__global__ void combine_kernel(const float* __restrict__ outPart, float* __restrict__ out) {
  int b = threadIdx.x;  // 64 threads
  float s = 0.f;
#pragma unroll
  for (int k = 0; k < 16; ++k) s += outPart[b * 16 + k];
  out[b] = s;
}

// ---------------------------------------------------------------------------
extern "C" void kernel_launch(void* const* d_in, const int* in_sizes, int n_in,
                              void* d_out, int out_size, void* d_ws, size_t ws_size,
                              hipStream_t stream) {
  (void)in_sizes; (void)n_in; (void)out_size; (void)ws_size;
  const float* x = (const float*)d_in[0];
  const float* y = (const float*)d_in[1];
  float* out = (float*)d_out;

  char* ws = (char*)d_ws;
  _Float16* Sh = (_Float16*)ws;                                // 32 MiB
  float* fregion = (float*)(ws + (size_t)NB * NS * NS * 2);
  float* U = fregion;                                          // 32768
  float* V = U + NB * NS;
  float* W = V + NB * NS;
  float* outPart = W + NB * NS;                                // 1024

  gemm_fused<<<512, 512, 0, stream>>>(x, y, Sh);

  for (int t = 1; t <= NITERS; ++t) {
    float f = 10.0f * (float)t;
    u_kernel<<<2048, 256, 0, stream>>>(Sh, W, U, f, t == 1 ? 1 : 0);
    v_kernel<<<1024, 256, 0, stream>>>(Sh, U, V, W, f, t == 1 ? 1 : 0,
                                       t == NITERS ? 1 : 0, outPart);
  }
  combine_kernel<<<1, 64, 0, stream>>>(outPart, out);
}

// Round 16
// 192.801 us; speedup vs baseline: 1.1632x; 1.1632x over previous
//
#include <hip/hip_runtime.h>
#include <hip/hip_fp16.h>

#define NB 64
#define NS 512
#define NH 1024
#define NITERS 10

// -log(512)
#define LOG_INV_NS (-6.238324625039508f)

using half8 = _Float16 __attribute__((ext_vector_type(8)));
using f32x4 = float __attribute__((ext_vector_type(4)));

// ---------------------------------------------------------------------------
// Fused GEMM: batched cosine scores, f16 out. 256x256 tile, 512 thr / 8 waves.
// R16: BK=64 (16 K-steps, 64 MFMA/wave/step) to halve per-barrier residual.
// Staging in two 32-col half-chunks per step (32 prefetch VGPRs, unchanged):
//   MFMA slice0 -> CAST(H0 of next) + GLOAD(next H1) -> MFMA slice1
//   -> CAST(H1 of next) + GLOAD(next+1 H0) -> lgkm drain -> raw s_barrier.
// LDS 149.5 KB (grid = 256 = #CUs, so 1 block/CU regardless -> LDS is free).
// In-kernel row norms; epilogue normalization; XCD-pinned decode.
__global__ __launch_bounds__(512) void gemm_fused(
    const float* __restrict__ x, const float* __restrict__ y,
    _Float16* __restrict__ Sh) {
  __shared__ _Float16 As[2][256][72];   // 73,728 B
  __shared__ _Float16 Bs[2][256][72];   // 73,728 B
  __shared__ float invA[256], invB[256];

  int blk = blockIdx.x;
  int b = blk & 63;                  // batch; blk%8 = b%8 -> XCD pinned
  int tile = blk >> 6;               // 0..3
  int tm = (tile >> 1) * 256, tn = (tile & 1) * 256;
  int tid = threadIdx.x;
  int wid = tid >> 6, lane = tid & 63;
  int wr = (wid >> 2) * 128;         // {0,128}
  int wc = (wid & 3) * 64;           // {0,64,128,192}
  int fr = lane & 15, fq = lane >> 4;

  int srow = tid >> 1;
  int skh = (tid & 1) * 16;
  const float* xb = x + ((size_t)b * NS + tm + srow) * NH + skh;
  const float* yb = y + ((size_t)b * NS + tn + srow) * NH + skh;

  f32x4 acc[8][4] = {};
  float4 rx[4], ry[4];
  float sqx = 0.f, sqy = 0.f;

#define GLOAD(K0)                                                     \
  do {                                                                \
    const float4* px = (const float4*)(xb + (K0));                    \
    const float4* py = (const float4*)(yb + (K0));                    \
    rx[0] = px[0]; rx[1] = px[1]; rx[2] = px[2]; rx[3] = px[3];       \
    ry[0] = py[0]; ry[1] = py[1]; ry[2] = py[2]; ry[3] = py[3];       \
  } while (0)

  // cast rx/ry -> f16, accumulate sumsq, write 16-col slab at col base COL
#define CAST_WRITE(BUF, COL)                                          \
  do {                                                                \
    alignas(16) _Float16 ta[16];                                      \
    alignas(16) _Float16 tb[16];                                      \
    _Pragma("unroll") for (int j = 0; j < 4; ++j) {                   \
      float4 v = rx[j];                                               \
      ta[4 * j + 0] = (_Float16)v.x; ta[4 * j + 1] = (_Float16)v.y;   \
      ta[4 * j + 2] = (_Float16)v.z; ta[4 * j + 3] = (_Float16)v.w;   \
      sqx += v.x * v.x + v.y * v.y + v.z * v.z + v.w * v.w;           \
    }                                                                 \
    _Pragma("unroll") for (int j = 0; j < 4; ++j) {                   \
      float4 v = ry[j];                                               \
      tb[4 * j + 0] = (_Float16)v.x; tb[4 * j + 1] = (_Float16)v.y;   \
      tb[4 * j + 2] = (_Float16)v.z; tb[4 * j + 3] = (_Float16)v.w;   \
      sqy += v.x * v.x + v.y * v.y + v.z * v.z + v.w * v.w;           \
    }                                                                 \
    *(half8*)&As[BUF][srow][(COL) + skh + 0] = *(half8*)&ta[0];       \
    *(half8*)&As[BUF][srow][(COL) + skh + 8] = *(half8*)&ta[8];       \
    *(half8*)&Bs[BUF][srow][(COL) + skh + 0] = *(half8*)&tb[0];       \
    *(half8*)&Bs[BUF][srow][(COL) + skh + 8] = *(half8*)&tb[8];       \
  } while (0)

  // prologue: stage chunk 0 (both halves) into buf 0; issue chunk1-H0 loads
  GLOAD(0);
  CAST_WRITE(0, 0);
  GLOAD(32);
  CAST_WRITE(0, 32);
  GLOAD(64);
  asm volatile("s_waitcnt lgkmcnt(0)" ::: "memory");
  __builtin_amdgcn_sched_barrier(0);
  __builtin_amdgcn_s_barrier();
  __builtin_amdgcn_sched_barrier(0);

  for (int s = 0; s < 16; ++s) {
    int cur = s & 1;
    // ---- MFMA slice 0 (cols 0-31 of buf[cur]) ----
    {
      half8 bf[4];
#pragma unroll
      for (int j = 0; j < 4; ++j)
        bf[j] = *(const half8*)&Bs[cur][wc + 16 * j + fr][8 * fq];
#pragma unroll
      for (int i = 0; i < 8; ++i) {
        half8 af = *(const half8*)&As[cur][wr + 16 * i + fr][8 * fq];
#pragma unroll
        for (int j = 0; j < 4; ++j)
          acc[i][j] = __builtin_amdgcn_mfma_f32_16x16x32_f16(af, bf[j], acc[i][j], 0, 0, 0);
      }
    }
    // ---- stage H0 of chunk s+1 (loads issued last step); issue its H1 ----
    if (s < 15) {
      CAST_WRITE(cur ^ 1, 0);
      GLOAD((s + 1) * 64 + 32);
    }
    // ---- MFMA slice 1 (cols 32-63 of buf[cur]) ----
    {
      half8 bf[4];
#pragma unroll
      for (int j = 0; j < 4; ++j)
        bf[j] = *(const half8*)&Bs[cur][wc + 16 * j + fr][32 + 8 * fq];
#pragma unroll
      for (int i = 0; i < 8; ++i) {
        half8 af = *(const half8*)&As[cur][wr + 16 * i + fr][32 + 8 * fq];
#pragma unroll
        for (int j = 0; j < 4; ++j)
          acc[i][j] = __builtin_amdgcn_mfma_f32_16x16x32_f16(af, bf[j], acc[i][j], 0, 0, 0);
      }
    }
    // ---- stage H1 of chunk s+1; issue H0 loads of chunk s+2 ----
    if (s < 15) {
      CAST_WRITE(cur ^ 1, 32);
      if (s < 14) GLOAD((s + 2) * 64);
    }
    asm volatile("s_waitcnt lgkmcnt(0)" ::: "memory");
    __builtin_amdgcn_sched_barrier(0);
    __builtin_amdgcn_s_barrier();
    __builtin_amdgcn_sched_barrier(0);
  }
#undef GLOAD
#undef CAST_WRITE

  // finalize row norms: two partials per row in adjacent lanes (tid, tid^1)
  sqx += __shfl_xor(sqx, 1, 64);
  sqy += __shfl_xor(sqy, 1, 64);
  if ((tid & 1) == 0) {
    invA[srow] = 1.0f / fmaxf(sqrtf(sqx), 1e-12f);
    invB[srow] = 1.0f / fmaxf(sqrtf(sqy), 1e-12f);
  }
  __syncthreads();

  // Epilogue: S = acc * invA[m] * invB[n], direct f16 stores.
  // C/D layout: col = lane&15 (n), row = (lane>>4)*4 + reg (m).
  _Float16* Sb = Sh + (size_t)b * NS * NS;
#pragma unroll
  for (int i = 0; i < 8; ++i)
#pragma unroll
    for (int j = 0; j < 4; ++j) {
      int rr = wr + 16 * i + 4 * fq;
      int cc = wc + 16 * j + fr;
      float ib = invB[cc];
#pragma unroll
      for (int p = 0; p < 4; ++p)
        Sb[(size_t)(tm + rr + p) * NS + tn + cc] =
            (_Float16)(acc[i][j][p] * invA[rr + p] * ib);
    }
}

// ---------------------------------------------------------------------------
// Kernel 4 (u/row step): 2048 blocks. first=1 -> W uniformly log(1/NS).
__global__ __launch_bounds__(256) void u_kernel(
    const _Float16* __restrict__ Sh, const float* __restrict__ W,
    float* __restrict__ U, float f, int first) {
  __shared__ float Wt[8][65];
  int blk = blockIdx.x;
  int bs = blk & 7, rest = blk >> 3;
  int rowgrp = rest & 31, bq = rest >> 5;
  int b = bq * 8 + bs;
  int t = threadIdx.x;
  if (!first) {
#pragma unroll
    for (int i = 0; i < 2; ++i) {
      int idx = t + 256 * i;
      Wt[idx & 7][idx >> 3] = W[b * NS + idx];
    }
    __syncthreads();
  }
  int w = t >> 6, l = t & 63;
  float wn[8];
#pragma unroll
  for (int e = 0; e < 8; ++e) wn[e] = first ? LOG_INV_NS : Wt[e][l];
  int m0 = rowgrp * 16 + w * 4;
  const _Float16* Sb = Sh + ((size_t)b * NS + m0) * NS + 8 * l;
  float sum[4] = {0.f, 0.f, 0.f, 0.f};
#pragma unroll
  for (int k = 0; k < 4; ++k) {
    half8 hv = *(const half8*)(Sb + (size_t)k * NS);
#pragma unroll
    for (int e = 0; e < 8; ++e) sum[k] += __expf(fmaf(f, (float)hv[e], wn[e]));
  }
#pragma unroll
  for (int o = 32; o; o >>= 1) {
#pragma unroll
    for (int k = 0; k < 4; ++k) sum[k] += __shfl_xor(sum[k], o, 64);
  }
  if (l == 0) {
#pragma unroll
    for (int k = 0; k < 4; ++k)
      U[b * NS + m0 + k] = LOG_INV_NS - __logf(sum[k]);
  }
}

// ---------------------------------------------------------------------------
// Kernel 5 (v/col step): 1024 blocks, high occupancy. first=1 -> vold = 0.
__global__ __launch_bounds__(256) void v_kernel(
    const _Float16* __restrict__ Sh, const float* __restrict__ U,
    float* __restrict__ V, float* __restrict__ W,
    float f, int first, int last, float* __restrict__ outPart) {
  __shared__ float Ul[NS];
  __shared__ float partC[64][33];
  __shared__ float partD[64][33];
  __shared__ float redC[4][33];
  __shared__ float redD[4][33];
  int blk = blockIdx.x;
  int b = blk & 63;
  int ng = blk >> 6;                // 0..15, 32 cols each
  int t = threadIdx.x;
  Ul[t] = U[b * NS + t];
  Ul[t + 256] = U[b * NS + t + 256];
  __syncthreads();

  int oct = t & 3;
  int mc = t >> 2;                  // m-chunk (8 rows), 0..63
  const _Float16* Sb = Sh + (size_t)b * NS * NS + (size_t)(mc * 8) * NS + ng * 32 + oct * 8;
  float c[8] = {}, d[8] = {};
#pragma unroll
  for (int i = 0; i < 8; ++i) {
    half8 hv = *(const half8*)(Sb + (size_t)i * NS);
    float um = Ul[mc * 8 + i];
#pragma unroll
    for (int e = 0; e < 8; ++e) {
      float sv = (float)hv[e];
      float ev = __expf(fmaf(f, sv, um));
      c[e] += ev;
      d[e] = fmaf(sv, ev, d[e]);
    }
  }
#pragma unroll
  for (int e = 0; e < 8; ++e) {
    partC[mc][oct * 8 + e] = c[e];
    partD[mc][oct * 8 + e] = d[e];
  }
  __syncthreads();
  {
    int ci = t & 31, seg = t >> 5;
    float cc = 0.f, dd = 0.f;
#pragma unroll
    for (int k = 0; k < 8; ++k) {
      cc += partC[seg * 8 + k][ci];
      dd += partD[seg * 8 + k][ci];
    }
    cc += __shfl_xor(cc, 32, 64);
    dd += __shfl_xor(dd, 32, 64);
    int w = t >> 6, l = t & 63;
    if (l < 32) { redC[w][l] = cc; redD[w][l] = dd; }
  }
  __syncthreads();
  if (t < 32) {
    float cc = redC[0][t] + redC[1][t] + redC[2][t] + redC[3][t];
    float vnew = LOG_INV_NS - __logf(cc);
    int n = b * NS + ng * 32 + t;
    float vold = first ? 0.f : V[n];
    V[n] = vnew;
    W[n] = 2.f * vnew - vold;
    if (last) {
      float dd = redD[0][t] + redD[1][t] + redD[2][t] + redD[3][t];
      float r = dd / cc;
      r += __shfl_xor(r, 16, 64);
      r += __shfl_xor(r, 8, 64);
      r += __shfl_xor(r, 4, 64);
      r += __shfl_xor(r, 2, 64);
      r += __shfl_xor(r, 1, 64);
      if (t == 0) outPart[b * 16 + ng] = r * (1.0f / (float)NS);
    }
  }
}

// ---------------------------------------------------------------------------
// Kernel 6: combine 16 partials per batch (deterministic)
__global__ void combine_kernel(const float* __restrict__ outPart, float* __restrict__ out) {
  int b = threadIdx.x;  // 64 threads
  float s = 0.f;
#pragma unroll
  for (int k = 0; k < 16; ++k) s += outPart[b * 16 + k];
  out[b] = s;
}

// ---------------------------------------------------------------------------
extern "C" void kernel_launch(void* const* d_in, const int* in_sizes, int n_in,
                              void* d_out, int out_size, void* d_ws, size_t ws_size,
                              hipStream_t stream) {
  (void)in_sizes; (void)n_in; (void)out_size; (void)ws_size;
  const float* x = (const float*)d_in[0];
  const float* y = (const float*)d_in[1];
  float* out = (float*)d_out;

  char* ws = (char*)d_ws;
  _Float16* Sh = (_Float16*)ws;                                // 32 MiB
  float* fregion = (float*)(ws + (size_t)NB * NS * NS * 2);
  float* U = fregion;                                          // 32768
  float* V = U + NB * NS;
  float* W = V + NB * NS;
  float* outPart = W + NB * NS;                                // 1024

  gemm_fused<<<256, 512, 0, stream>>>(x, y, Sh);

  for (int t = 1; t <= NITERS; ++t) {
    float f = 10.0f * (float)t;
    u_kernel<<<2048, 256, 0, stream>>>(Sh, W, U, f, t == 1 ? 1 : 0);
    v_kernel<<<1024, 256, 0, stream>>>(Sh, U, V, W, f, t == 1 ? 1 : 0,
                                       t == NITERS ? 1 : 0, outPart);
  }
  combine_kernel<<<1, 64, 0, stream>>>(outPart, out);
}